// Round 1
// baseline (5998.857 us; speedup 1.0000x reference)
//
#include <hip/hip_runtime.h>
#include <math.h>

// AttnBlock: GroupNorm -> QKV 1x1 conv -> spatial self-attention -> proj 1x1 conv + residual
// Shapes: x (4, 512, 64, 64) fp32. B=4, C=512, N=HW=4096, 32 groups of 16 ch.
// Round 1: correct fp32 baseline, modular kernels (MFMA conversion comes later).

#define BATCH 4
#define CH    512
#define NPOS  4096
#define NGRP  32
#define CPG   16
#define GSIZE (CPG * NPOS)   // 65536 elements per (batch, group), contiguous in memory

// ---------------------------------------------------------------------------
// K1: GroupNorm statistics. One block per (b, g); the group's data is a
// contiguous 65536-float segment. Writes mean[128], rstd[128].
// ---------------------------------------------------------------------------
__global__ __launch_bounds__(256) void gn_stats_k(const float* __restrict__ x,
                                                  float* __restrict__ stats) {
    int bg = blockIdx.x;
    const float4* xp = reinterpret_cast<const float4*>(x + (size_t)bg * GSIZE);
    float s1 = 0.f, s2 = 0.f;
    for (int i = threadIdx.x; i < GSIZE / 4; i += 256) {
        float4 v = xp[i];
        s1 += v.x + v.y + v.z + v.w;
        s2 += v.x * v.x + v.y * v.y + v.z * v.z + v.w * v.w;
    }
    for (int off = 32; off > 0; off >>= 1) {
        s1 += __shfl_down(s1, off);
        s2 += __shfl_down(s2, off);
    }
    __shared__ float r1[4], r2[4];
    int wid = threadIdx.x >> 6;
    if ((threadIdx.x & 63) == 0) { r1[wid] = s1; r2[wid] = s2; }
    __syncthreads();
    if (threadIdx.x == 0) {
        float t1 = r1[0] + r1[1] + r1[2] + r1[3];
        float t2 = r2[0] + r2[1] + r2[2] + r2[3];
        float mean = t1 / (float)GSIZE;
        float var  = t2 / (float)GSIZE - mean * mean;
        stats[bg]       = mean;
        stats[128 + bg] = rsqrtf(var + 1e-6f);
    }
}

// ---------------------------------------------------------------------------
// K2: QKV GEMM with GroupNorm fused into the B-tile load.
// out[sel][b][o][m] = bias[o] + sum_c W[o][c] * hn(b,c,m)
// grid (N/64, C/64, 3*B); block 256 (16x16 threads, 4x4 microtile).
// ---------------------------------------------------------------------------
__global__ __launch_bounds__(256) void qkv_k(
    const float* __restrict__ x,
    const float* __restrict__ gamma, const float* __restrict__ beta,
    const float* __restrict__ Wq, const float* __restrict__ bq,
    const float* __restrict__ Wk, const float* __restrict__ bk,
    const float* __restrict__ Wv, const float* __restrict__ bv,
    const float* __restrict__ stats,
    float* __restrict__ qb, float* __restrict__ kb, float* __restrict__ vb) {
    int m0  = blockIdx.x * 64;
    int o0  = blockIdx.y * 64;
    int b   = blockIdx.z & 3;
    int sel = blockIdx.z >> 2;
    const float* W    = sel == 0 ? Wq : (sel == 1 ? Wk : Wv);
    const float* bias = sel == 0 ? bq : (sel == 1 ? bk : bv);
    float* outp       = sel == 0 ? qb : (sel == 1 ? kb : vb);

    __shared__ float Ws[16][68];  // [cc][o_local], 68: 16B-aligned rows, 2-way banks
    __shared__ float Hs[16][68];  // [cc][m_local]
    int t = threadIdx.x;
    int tx = t & 15, ty = t >> 4;
    float acc[4][4] = {};
    const float* xb = x + (size_t)b * CH * NPOS;

    for (int kc = 0; kc < CH; kc += 16) {
#pragma unroll
        for (int it = 0; it < 4; ++it) {
            int r = ty + it * 16;
            Ws[tx][r] = W[(size_t)(o0 + r) * CH + kc + tx];
        }
#pragma unroll
        for (int it = 0; it < 4; ++it) {
            int f = it * 256 + t;
            int cc = f >> 6, mm = f & 63;
            int ch = kc + cc;
            float val = xb[(size_t)ch * NPOS + m0 + mm];
            int bg = b * NGRP + (ch >> 4);
            Hs[cc][mm] = (val - stats[bg]) * stats[128 + bg] * gamma[ch] + beta[ch];
        }
        __syncthreads();
#pragma unroll 8
        for (int cc = 0; cc < 16; ++cc) {
            float4 a  = *reinterpret_cast<const float4*>(&Ws[cc][ty * 4]);
            float4 bb = *reinterpret_cast<const float4*>(&Hs[cc][tx * 4]);
            float av[4] = {a.x, a.y, a.z, a.w};
            float bv4[4] = {bb.x, bb.y, bb.z, bb.w};
#pragma unroll
            for (int i = 0; i < 4; ++i)
#pragma unroll
                for (int j = 0; j < 4; ++j) acc[i][j] += av[i] * bv4[j];
        }
        __syncthreads();
    }
#pragma unroll
    for (int i = 0; i < 4; ++i) {
        int o = o0 + ty * 4 + i;
        float bia = bias[o];
        float4 st;
        st.x = acc[i][0] + bia; st.y = acc[i][1] + bia;
        st.z = acc[i][2] + bia; st.w = acc[i][3] + bia;
        *reinterpret_cast<float4*>(&outp[((size_t)b * CH + o) * NPOS + m0 + tx * 4]) = st;
    }
}

// ---------------------------------------------------------------------------
// K3: flash attention, fp32. grid (N/32, B); block 512 (8 waves).
// Per block: 32 query rows, full C=512 accumulator in registers
// (thread t: m = t>>4, c = (t&15)*2 + 32*jj + {0,1}).
// K/V streamed through LDS in 64-channel chunks; TN=64 keys per tile.
// Writes attn output TRANSPOSED: aoT[b][m][c] (coalesced float2 stores).
// ---------------------------------------------------------------------------
__global__ __launch_bounds__(512) void attn_k(const float* __restrict__ qb,
                                              const float* __restrict__ kb,
                                              const float* __restrict__ vb,
                                              float* __restrict__ aoT) {
    int b  = blockIdx.y;
    int m0 = blockIdx.x * 32;
    __shared__ float sq[CH * 32];     // q tile [c][m], 64 KB
    __shared__ float skv[64 * 66];    // k/v chunk [cc][nn], stride 66 (8B-aligned rows)
    __shared__ float ss[32 * 65];     // scores / probs [m][n]
    __shared__ float mrun[32], lrun[32], alphas[32];
    int t = threadIdx.x;
    const float* qB = qb + (size_t)b * CH * NPOS;
    const float* kB = kb + (size_t)b * CH * NPOS;
    const float* vB = vb + (size_t)b * CH * NPOS;

    for (int it = 0; it < 32; ++it) {
        int f = it * 512 + t;
        sq[f] = qB[(size_t)(f >> 5) * NPOS + m0 + (f & 31)];
    }
    if (t < 32) { mrun[t] = -1e30f; lrun[t] = 0.f; }

    float acc0[16], acc1[16];
#pragma unroll
    for (int jj = 0; jj < 16; ++jj) { acc0[jj] = 0.f; acc1[jj] = 0.f; }

    int m_s = (t & 15) * 2;   // s-compute: 2x2 microtile at (m_s, n_s)
    int n_s = (t >> 4) * 2;
    int m_a = t >> 4;         // acc / softmax row
    int j_a = t & 15;
    __syncthreads();
    const float scale = 0.044194173824159216f;  // 512^-0.5

    for (int nt = 0; nt < 64; ++nt) {
        int n0 = nt * 64;
        float s00 = 0.f, s01 = 0.f, s10 = 0.f, s11 = 0.f;
        for (int ch2 = 0; ch2 < 8; ++ch2) {
            __syncthreads();  // previous skv consumers done
            int c0 = ch2 * 64;
#pragma unroll
            for (int it = 0; it < 8; ++it) {
                int f = it * 512 + t;
                int cc = f >> 6, nn = f & 63;
                skv[cc * 66 + nn] = kB[(size_t)(c0 + cc) * NPOS + n0 + nn];
            }
            __syncthreads();
#pragma unroll 8
            for (int cc = 0; cc < 64; ++cc) {
                float2 qv = *reinterpret_cast<const float2*>(&sq[(c0 + cc) * 32 + m_s]);
                float2 kv = *reinterpret_cast<const float2*>(&skv[cc * 66 + n_s]);
                s00 += qv.x * kv.x; s01 += qv.x * kv.y;
                s10 += qv.y * kv.x; s11 += qv.y * kv.y;
            }
        }
        ss[m_s * 65 + n_s]           = s00 * scale;
        ss[m_s * 65 + n_s + 1]       = s01 * scale;
        ss[(m_s + 1) * 65 + n_s]     = s10 * scale;
        ss[(m_s + 1) * 65 + n_s + 1] = s11 * scale;
        __syncthreads();
        // online softmax: row r handled by 16 threads (j = lane-in-group)
        {
            int r = m_a, j = j_a;
            float v0 = ss[r * 65 + j];
            float v1 = ss[r * 65 + j + 16];
            float v2 = ss[r * 65 + j + 32];
            float v3 = ss[r * 65 + j + 48];
            float mx = fmaxf(fmaxf(v0, v1), fmaxf(v2, v3));
            for (int off = 8; off > 0; off >>= 1) mx = fmaxf(mx, __shfl_xor(mx, off));
            float mold = mrun[r];
            float mnew = fmaxf(mold, mx);
            float p0 = __expf(v0 - mnew), p1 = __expf(v1 - mnew);
            float p2 = __expf(v2 - mnew), p3 = __expf(v3 - mnew);
            ss[r * 65 + j]      = p0;
            ss[r * 65 + j + 16] = p1;
            ss[r * 65 + j + 32] = p2;
            ss[r * 65 + j + 48] = p3;
            float ls = p0 + p1 + p2 + p3;
            for (int off = 8; off > 0; off >>= 1) ls += __shfl_xor(ls, off);
            if (j == 0) {
                float alpha = __expf(mold - mnew);
                alphas[r] = alpha;
                lrun[r] = lrun[r] * alpha + ls;
                mrun[r] = mnew;
            }
        }
        __syncthreads();
        float al = alphas[m_a];
#pragma unroll
        for (int jj = 0; jj < 16; ++jj) { acc0[jj] *= al; acc1[jj] *= al; }
        // PV: stream v in 64-channel chunks; thread's channels in chunk ch2 are
        // jj = 2*ch2 (lc = 2*j_a) and jj = 2*ch2+1 (lc = 2*j_a+32).
#pragma unroll
        for (int ch2 = 0; ch2 < 8; ++ch2) {
            __syncthreads();
            int c0 = ch2 * 64;
#pragma unroll
            for (int it = 0; it < 8; ++it) {
                int f = it * 512 + t;
                int cc = f >> 6, nn = f & 63;
                skv[cc * 66 + nn] = vB[(size_t)(c0 + cc) * NPOS + n0 + nn];
            }
            __syncthreads();
            int lc0 = j_a * 2;
            int lc1 = j_a * 2 + 32;
            float a00 = acc0[2 * ch2],     a01 = acc1[2 * ch2];
            float a10 = acc0[2 * ch2 + 1], a11 = acc1[2 * ch2 + 1];
#pragma unroll 4
            for (int n = 0; n < 64; ++n) {
                float p = ss[m_a * 65 + n];
                a00 += p * skv[lc0 * 66 + n];
                a01 += p * skv[(lc0 + 1) * 66 + n];
                a10 += p * skv[lc1 * 66 + n];
                a11 += p * skv[(lc1 + 1) * 66 + n];
            }
            acc0[2 * ch2] = a00;     acc1[2 * ch2] = a01;
            acc0[2 * ch2 + 1] = a10; acc1[2 * ch2 + 1] = a11;
        }
    }
    float inv = 1.0f / lrun[m_a];
    float* aoRow = aoT + ((size_t)b * NPOS + (m0 + m_a)) * CH;
#pragma unroll
    for (int jj = 0; jj < 16; ++jj) {
        int c = j_a * 2 + 32 * jj;
        float2 st;
        st.x = acc0[jj] * inv;
        st.y = acc1[jj] * inv;
        *reinterpret_cast<float2*>(&aoRow[c]) = st;
    }
}

// ---------------------------------------------------------------------------
// K4: proj 1x1 conv + bias + residual. Input aoT[b][m][c] (transposed).
// out[b][o][m] = x[b][o][m] + bp[o] + sum_c Wp[o][c] * aoT[b][m][c]
// ---------------------------------------------------------------------------
__global__ __launch_bounds__(256) void proj_k(const float* __restrict__ aoT,
                                              const float* __restrict__ Wp,
                                              const float* __restrict__ bp,
                                              const float* __restrict__ x,
                                              float* __restrict__ out) {
    int m0 = blockIdx.x * 64;
    int o0 = blockIdx.y * 64;
    int b  = blockIdx.z;
    __shared__ float Ws[16][68];
    __shared__ float Hs[16][68];
    int t = threadIdx.x, tx = t & 15, ty = t >> 4;
    float acc[4][4] = {};
    const float* aB = aoT + (size_t)b * NPOS * CH;

    for (int kc = 0; kc < CH; kc += 16) {
#pragma unroll
        for (int it = 0; it < 4; ++it) {
            int r = ty + it * 16;
            Ws[tx][r] = Wp[(size_t)(o0 + r) * CH + kc + tx];
        }
#pragma unroll
        for (int it = 0; it < 4; ++it) {
            int f = it * 256 + t;
            int cc = f & 15, mm = f >> 4;
            Hs[cc][mm] = aB[(size_t)(m0 + mm) * CH + kc + cc];
        }
        __syncthreads();
#pragma unroll 8
        for (int cc = 0; cc < 16; ++cc) {
            float4 a  = *reinterpret_cast<const float4*>(&Ws[cc][ty * 4]);
            float4 bb = *reinterpret_cast<const float4*>(&Hs[cc][tx * 4]);
            float av[4] = {a.x, a.y, a.z, a.w};
            float bv4[4] = {bb.x, bb.y, bb.z, bb.w};
#pragma unroll
            for (int i = 0; i < 4; ++i)
#pragma unroll
                for (int j = 0; j < 4; ++j) acc[i][j] += av[i] * bv4[j];
        }
        __syncthreads();
    }
#pragma unroll
    for (int i = 0; i < 4; ++i) {
        int o = o0 + ty * 4 + i;
        float bia = bp[o];
        size_t base = ((size_t)b * CH + o) * NPOS + m0 + tx * 4;
        float4 xv = *reinterpret_cast<const float4*>(&x[base]);
        float4 st;
        st.x = acc[i][0] + bia + xv.x; st.y = acc[i][1] + bia + xv.y;
        st.z = acc[i][2] + bia + xv.z; st.w = acc[i][3] + bia + xv.w;
        *reinterpret_cast<float4*>(&out[base]) = st;
    }
}

// ---------------------------------------------------------------------------
extern "C" void kernel_launch(void* const* d_in, const int* in_sizes, int n_in,
                              void* d_out, int out_size, void* d_ws, size_t ws_size,
                              hipStream_t stream) {
    const float* x     = (const float*)d_in[0];
    const float* gamma = (const float*)d_in[1];
    const float* beta  = (const float*)d_in[2];
    const float* Wq    = (const float*)d_in[3];
    const float* bq    = (const float*)d_in[4];
    const float* Wk    = (const float*)d_in[5];
    const float* bk    = (const float*)d_in[6];
    const float* Wv    = (const float*)d_in[7];
    const float* bv    = (const float*)d_in[8];
    const float* Wp    = (const float*)d_in[9];
    const float* bp    = (const float*)d_in[10];
    float* out = (float*)d_out;
    float* ws  = (float*)d_ws;

    const size_t SZ = (size_t)BATCH * CH * NPOS;       // 8,388,608 floats
    const size_t need = (4 * SZ + 256) * sizeof(float); // ~128 MB
    if (ws_size < need) return;  // fail loudly (absmax) rather than corrupt

    float* qb    = ws;
    float* kb    = qb + SZ;
    float* vb    = kb + SZ;
    float* aoT   = vb + SZ;        // [b][m][c]
    float* stats = aoT + SZ;       // mean[128], rstd[128]

    gn_stats_k<<<128, 256, 0, stream>>>(x, stats);
    qkv_k<<<dim3(64, 8, 12), 256, 0, stream>>>(x, gamma, beta, Wq, bq, Wk, bk,
                                               Wv, bv, stats, qb, kb, vb);
    attn_k<<<dim3(128, 4), 512, 0, stream>>>(qb, kb, vb, aoT);
    proj_k<<<dim3(64, 8, 4), 256, 0, stream>>>(aoT, Wp, bp, x, out);
}

// Round 5
// 1613.967 us; speedup vs baseline: 3.7168x; 3.7168x over previous
//
#include <hip/hip_runtime.h>
#include <math.h>

// AttnBlock: GroupNorm -> QKV 1x1 conv -> spatial self-attention -> proj 1x1 conv + residual
// x (4, 512, 64, 64) fp32. B=4, C=512, N=HW=4096, 32 groups of 16 ch.
// Round 5: identical to round 2 (three bench infra failures — resubmit).
// attention on bf16 MFMA (16x16x32), flash-style, P-via-swizzled-LDS.

#define BATCH 4
#define CH    512
#define NPOS  4096
#define NGRP  32
#define GSIZE (16 * NPOS)

typedef __attribute__((ext_vector_type(8))) short bf16x8;
typedef __attribute__((ext_vector_type(4))) float f32x4;

__device__ __forceinline__ ushort f2b(float x) {   // fp32 -> bf16 RNE
    uint u = __float_as_uint(x);
    u += 0x7fff + ((u >> 16) & 1);
    return (ushort)(u >> 16);
}

// ---------------------------------------------------------------------------
// K1: GroupNorm statistics. One block per (b, g) contiguous 65536-float segment.
// ---------------------------------------------------------------------------
__global__ __launch_bounds__(256) void gn_stats_k(const float* __restrict__ x,
                                                  float* __restrict__ stats) {
    int bg = blockIdx.x;
    const float4* xp = reinterpret_cast<const float4*>(x + (size_t)bg * GSIZE);
    float s1 = 0.f, s2 = 0.f;
    for (int i = threadIdx.x; i < GSIZE / 4; i += 256) {
        float4 v = xp[i];
        s1 += v.x + v.y + v.z + v.w;
        s2 += v.x * v.x + v.y * v.y + v.z * v.z + v.w * v.w;
    }
    for (int off = 32; off > 0; off >>= 1) {
        s1 += __shfl_down(s1, off);
        s2 += __shfl_down(s2, off);
    }
    __shared__ float r1[4], r2[4];
    int wid = threadIdx.x >> 6;
    if ((threadIdx.x & 63) == 0) { r1[wid] = s1; r2[wid] = s2; }
    __syncthreads();
    if (threadIdx.x == 0) {
        float t1 = r1[0] + r1[1] + r1[2] + r1[3];
        float t2 = r2[0] + r2[1] + r2[2] + r2[3];
        float mean = t1 / (float)GSIZE;
        float var  = t2 / (float)GSIZE - mean * mean;
        stats[bg]       = mean;
        stats[128 + bg] = rsqrtf(var + 1e-6f);
    }
}

// ---------------------------------------------------------------------------
// K2: QKV GEMM, GroupNorm fused into B-tile load. bf16 outputs in MFMA layouts:
//   qT[b][m][c] (pre-scaled by 512^-0.5), kT[b][n][c], vB[b][c][n].
// grid (N/64, C/64, 3*B); block 256.
// ---------------------------------------------------------------------------
__global__ __launch_bounds__(256) void qkv_k(
    const float* __restrict__ x,
    const float* __restrict__ gamma, const float* __restrict__ beta,
    const float* __restrict__ Wq, const float* __restrict__ bq,
    const float* __restrict__ Wk, const float* __restrict__ bk,
    const float* __restrict__ Wv, const float* __restrict__ bv,
    const float* __restrict__ stats,
    ushort* __restrict__ qT, ushort* __restrict__ kT, ushort* __restrict__ vB) {
    int m0  = blockIdx.x * 64;
    int o0  = blockIdx.y * 64;
    int b   = blockIdx.z & 3;
    int sel = blockIdx.z >> 2;
    const float* W    = sel == 0 ? Wq : (sel == 1 ? Wk : Wv);
    const float* bias = sel == 0 ? bq : (sel == 1 ? bk : bv);

    __shared__ float Ws[16][68];  // [cc][o_local]
    __shared__ float Hs[16][68];  // [cc][m_local]
    int t = threadIdx.x, tx = t & 15, ty = t >> 4;
    float acc[4][4] = {};
    const float* xb = x + (size_t)b * CH * NPOS;

    // orientation: for q/k the microtile is (m x o) so the bf16 store to
    // [m][c] layout is coalesced; for v it is (o x m) for the [c][n] layout.
    const float (*At)[68] = (sel == 2) ? Ws : Hs;
    const float (*Bt)[68] = (sel == 2) ? Hs : Ws;

    for (int kc = 0; kc < CH; kc += 16) {
#pragma unroll
        for (int it = 0; it < 4; ++it) {
            int r = ty + it * 16;
            Ws[tx][r] = W[(size_t)(o0 + r) * CH + kc + tx];
        }
#pragma unroll
        for (int it = 0; it < 4; ++it) {
            int f = it * 256 + t;
            int cc = f >> 6, mm = f & 63;
            int ch = kc + cc;
            float val = xb[(size_t)ch * NPOS + m0 + mm];
            int bg = b * NGRP + (ch >> 4);
            Hs[cc][mm] = (val - stats[bg]) * stats[128 + bg] * gamma[ch] + beta[ch];
        }
        __syncthreads();
#pragma unroll 8
        for (int cc = 0; cc < 16; ++cc) {
            float4 a  = *reinterpret_cast<const float4*>(&At[cc][ty * 4]);
            float4 bb = *reinterpret_cast<const float4*>(&Bt[cc][tx * 4]);
            float av[4]  = {a.x, a.y, a.z, a.w};
            float bv4[4] = {bb.x, bb.y, bb.z, bb.w};
#pragma unroll
            for (int i = 0; i < 4; ++i)
#pragma unroll
                for (int j = 0; j < 4; ++j) acc[i][j] += av[i] * bv4[j];
        }
        __syncthreads();
    }
    if (sel == 2) {
        // rows = o (ty), cols = m (tx): vB[(b*CH+o)*NPOS + m]
#pragma unroll
        for (int i = 0; i < 4; ++i) {
            int o = o0 + ty * 4 + i;
            float bia = bias[o];
            ushort4 st = make_ushort4(f2b(acc[i][0] + bia), f2b(acc[i][1] + bia),
                                      f2b(acc[i][2] + bia), f2b(acc[i][3] + bia));
            *reinterpret_cast<ushort4*>(&vB[((size_t)b * CH + o) * NPOS + m0 + tx * 4]) = st;
        }
    } else {
        // rows = m (ty), cols = o (tx): qT/kT[(b*NPOS+m)*CH + o]
        float4 b4 = *reinterpret_cast<const float4*>(&bias[o0 + tx * 4]);
        float sc = (sel == 0) ? 0.044194173824159216f : 1.0f;  // 512^-0.5 folded into q
        ushort* outp = (sel == 0) ? qT : kT;
#pragma unroll
        for (int i = 0; i < 4; ++i) {
            int m = m0 + ty * 4 + i;
            ushort4 st = make_ushort4(f2b((acc[i][0] + b4.x) * sc),
                                      f2b((acc[i][1] + b4.y) * sc),
                                      f2b((acc[i][2] + b4.z) * sc),
                                      f2b((acc[i][3] + b4.w) * sc));
            *reinterpret_cast<ushort4*>(&outp[((size_t)b * NPOS + m) * CH + o0 + tx * 4]) = st;
        }
    }
}

// ---------------------------------------------------------------------------
// K3: flash attention on MFMA. grid (N/64, B); block 512 (8 waves).
// Wave w: m-subtile ms=w&3 (16 query rows, Q frags in regs), half nh=w>>2:
//   scores for n-cols [32nh,32nh+32), PV for c-cols [256nh,256nh+256).
// K/V fragments read direct from global (L2/L3-resident). P through LDS with
// XOR swizzle (row-major [16][64] bf16 tile is a 16-way conflict otherwise).
// MFMA 16x16x32 layouts: A row=l&15 k=8*(l>>4)+j; B col=l&15 same k;
// D col=l&15, row=4*(l>>4)+reg (HW-verified).
// ---------------------------------------------------------------------------
__global__ __launch_bounds__(512, 2) void attn_k(
    const ushort* __restrict__ qT, const ushort* __restrict__ kT,
    const ushort* __restrict__ vB, float* __restrict__ aoT) {
    __shared__ ushort P_lds[4][1024];      // per-m-subtile [16][64] bf16, swizzled
    __shared__ float mpart[4][2][16];
    __shared__ float lpart[4][2][16];

    int t = threadIdx.x;
    int l = t & 63, w = t >> 6;
    int ms = w & 3, nh = w >> 2;
    int b = blockIdx.y, m0 = blockIdx.x * 64;
    int lr = l & 15, lg = l >> 4;

    // Q fragments: 16 k-steps covering c=0..511 for this wave's 16 rows.
    const ushort* qrow = qT + ((size_t)(b * NPOS + m0 + 16 * ms + lr)) * CH + lg * 8;
    bf16x8 qf[16];
#pragma unroll
    for (int ks = 0; ks < 16; ++ks) qf[ks] = *(const bf16x8*)(qrow + ks * 32);

    const ushort* kbase = kT + ((size_t)(b * NPOS + 32 * nh + lr)) * CH + lg * 8;
    const ushort* vbase = vB + ((size_t)(b * CH + 256 * nh + lr)) * NPOS + lg * 8;
    ushort* Pms = &P_lds[ms][0];

    f32x4 acc[16];
#pragma unroll
    for (int i = 0; i < 16; ++i) acc[i] = (f32x4){0.f, 0.f, 0.f, 0.f};
    float m_run[4], l_run[4];
#pragma unroll
    for (int r = 0; r < 4; ++r) { m_run[r] = -1e30f; l_run[r] = 0.f; }

    for (int it = 0; it < 64; ++it) {
        int n0 = it * 64;
        // ---- scores: S[16 rows][32 cols] = Q . K^T (q pre-scaled) ----
        f32x4 s0 = {0.f, 0.f, 0.f, 0.f}, s1 = {0.f, 0.f, 0.f, 0.f};
        const ushort* k0 = kbase + (size_t)n0 * CH;
#pragma unroll
        for (int ks = 0; ks < 16; ++ks) {
            bf16x8 kf0 = *(const bf16x8*)(k0 + ks * 32);
            bf16x8 kf1 = *(const bf16x8*)(k0 + 16 * CH + ks * 32);
            s0 = __builtin_amdgcn_mfma_f32_16x16x32_bf16(qf[ks], kf0, s0, 0, 0, 0);
            s1 = __builtin_amdgcn_mfma_f32_16x16x32_bf16(qf[ks], kf1, s1, 0, 0, 0);
        }
        // ---- online softmax (rows shared between waves w and w^4) ----
        float pm[4];
#pragma unroll
        for (int r = 0; r < 4; ++r) pm[r] = fmaxf(s0[r], s1[r]);
#pragma unroll
        for (int off = 1; off < 16; off <<= 1)
#pragma unroll
            for (int r = 0; r < 4; ++r) pm[r] = fmaxf(pm[r], __shfl_xor(pm[r], off));
        if (lr == 0) {
#pragma unroll
            for (int r = 0; r < 4; ++r) mpart[ms][nh][4 * lg + r] = pm[r];
        }
        __syncthreads();
        float mnew[4], alpha[4];
#pragma unroll
        for (int r = 0; r < 4; ++r) {
            float mt = fmaxf(mpart[ms][0][4 * lg + r], mpart[ms][1][4 * lg + r]);
            mnew[r]  = fmaxf(m_run[r], mt);
            alpha[r] = __expf(m_run[r] - mnew[r]);
            m_run[r] = mnew[r];
        }
        float p0[4], p1[4], ps[4];
#pragma unroll
        for (int r = 0; r < 4; ++r) {
            p0[r] = __expf(s0[r] - mnew[r]);
            p1[r] = __expf(s1[r] - mnew[r]);
            ps[r] = p0[r] + p1[r];
        }
#pragma unroll
        for (int off = 1; off < 16; off <<= 1)
#pragma unroll
            for (int r = 0; r < 4; ++r) ps[r] += __shfl_xor(ps[r], off);
        if (lr == 0) {
#pragma unroll
            for (int r = 0; r < 4; ++r) lpart[ms][nh][4 * lg + r] = ps[r];
        }
        // P -> LDS (bf16), byte ^= (row&7)<<4 swizzle
#pragma unroll
        for (int r = 0; r < 4; ++r) {
            int row = 4 * lg + r;
            int sr  = (row & 7) << 4;
            int c0b = (64 * nh + 2 * lr) ^ sr;
            int c1b = (64 * nh + 32 + 2 * lr) ^ sr;
            Pms[(row * 128 + c0b) >> 1] = f2b(p0[r]);
            Pms[(row * 128 + c1b) >> 1] = f2b(p1[r]);
        }
        __syncthreads();
#pragma unroll
        for (int r = 0; r < 4; ++r) {
            float lsum = lpart[ms][0][4 * lg + r] + lpart[ms][1][4 * lg + r];
            l_run[r] = l_run[r] * alpha[r] + lsum;
        }
#pragma unroll
        for (int i = 0; i < 16; ++i) {
            acc[i][0] *= alpha[0]; acc[i][1] *= alpha[1];
            acc[i][2] *= alpha[2]; acc[i][3] *= alpha[3];
        }
        // ---- PV: O[16 rows][256 c-half] += P[16][64] . V^T ----
        bf16x8 pa0, pa1;
        {
            int sr = (lr & 7) << 4;
            pa0 = *(const bf16x8*)((const char*)Pms + lr * 128 + ((lg * 16) ^ sr));
            pa1 = *(const bf16x8*)((const char*)Pms + lr * 128 + ((lg * 16 + 64) ^ sr));
        }
        const ushort* v0 = vbase + n0;
#pragma unroll
        for (int cs = 0; cs < 16; ++cs) {
            bf16x8 vf0 = *(const bf16x8*)(v0 + (size_t)cs * 16 * NPOS);
            bf16x8 vf1 = *(const bf16x8*)(v0 + (size_t)cs * 16 * NPOS + 32);
            acc[cs] = __builtin_amdgcn_mfma_f32_16x16x32_bf16(pa0, vf0, acc[cs], 0, 0, 0);
            acc[cs] = __builtin_amdgcn_mfma_f32_16x16x32_bf16(pa1, vf1, acc[cs], 0, 0, 0);
        }
    }
    // epilogue: normalize, store fp32 aoT[b][m][c]
    float inv[4];
#pragma unroll
    for (int r = 0; r < 4; ++r) inv[r] = 1.0f / l_run[r];
    float* aorow = aoT + ((size_t)(b * NPOS + m0 + 16 * ms + 4 * lg)) * CH + 256 * nh + lr;
#pragma unroll
    for (int cs = 0; cs < 16; ++cs)
#pragma unroll
        for (int r = 0; r < 4; ++r)
            aorow[(size_t)r * CH + 16 * cs] = acc[cs][r] * inv[r];
}

// ---------------------------------------------------------------------------
// K4: proj 1x1 conv + bias + residual. Input aoT[b][m][c] fp32.
// ---------------------------------------------------------------------------
__global__ __launch_bounds__(256) void proj_k(const float* __restrict__ aoT,
                                              const float* __restrict__ Wp,
                                              const float* __restrict__ bp,
                                              const float* __restrict__ x,
                                              float* __restrict__ out) {
    int m0 = blockIdx.x * 64;
    int o0 = blockIdx.y * 64;
    int b  = blockIdx.z;
    __shared__ float Ws[16][68];
    __shared__ float Hs[16][68];
    int t = threadIdx.x, tx = t & 15, ty = t >> 4;
    float acc[4][4] = {};
    const float* aB = aoT + (size_t)b * NPOS * CH;

    for (int kc = 0; kc < CH; kc += 16) {
#pragma unroll
        for (int it = 0; it < 4; ++it) {
            int r = ty + it * 16;
            Ws[tx][r] = Wp[(size_t)(o0 + r) * CH + kc + tx];
        }
#pragma unroll
        for (int it = 0; it < 4; ++it) {
            int f = it * 256 + t;
            int cc = f & 15, mm = f >> 4;
            Hs[cc][mm] = aB[(size_t)(m0 + mm) * CH + kc + cc];
        }
        __syncthreads();
#pragma unroll 8
        for (int cc = 0; cc < 16; ++cc) {
            float4 a  = *reinterpret_cast<const float4*>(&Ws[cc][ty * 4]);
            float4 bb = *reinterpret_cast<const float4*>(&Hs[cc][tx * 4]);
            float av[4]  = {a.x, a.y, a.z, a.w};
            float bv4[4] = {bb.x, bb.y, bb.z, bb.w};
#pragma unroll
            for (int i = 0; i < 4; ++i)
#pragma unroll
                for (int j = 0; j < 4; ++j) acc[i][j] += av[i] * bv4[j];
        }
        __syncthreads();
    }
#pragma unroll
    for (int i = 0; i < 4; ++i) {
        int o = o0 + ty * 4 + i;
        float bia = bp[o];
        size_t base = ((size_t)b * CH + o) * NPOS + m0 + tx * 4;
        float4 xv = *reinterpret_cast<const float4*>(&x[base]);
        float4 st;
        st.x = acc[i][0] + bia + xv.x; st.y = acc[i][1] + bia + xv.y;
        st.z = acc[i][2] + bia + xv.z; st.w = acc[i][3] + bia + xv.w;
        *reinterpret_cast<float4*>(&out[base]) = st;
    }
}

// ---------------------------------------------------------------------------
extern "C" void kernel_launch(void* const* d_in, const int* in_sizes, int n_in,
                              void* d_out, int out_size, void* d_ws, size_t ws_size,
                              hipStream_t stream) {
    const float* x     = (const float*)d_in[0];
    const float* gamma = (const float*)d_in[1];
    const float* beta  = (const float*)d_in[2];
    const float* Wq    = (const float*)d_in[3];
    const float* bq    = (const float*)d_in[4];
    const float* Wk    = (const float*)d_in[5];
    const float* bk    = (const float*)d_in[6];
    const float* Wv    = (const float*)d_in[7];
    const float* bv    = (const float*)d_in[8];
    const float* Wp    = (const float*)d_in[9];
    const float* bp    = (const float*)d_in[10];
    float* out = (float*)d_out;

    const size_t SZ = (size_t)BATCH * CH * NPOS;          // 8,388,608
    const size_t need = SZ * 2 * 3 + SZ * 4 + 1024;       // ~84 MB
    if (ws_size < need) return;

    ushort* qT  = (ushort*)d_ws;         // [b][m][c] bf16 (pre-scaled)
    ushort* kT  = qT + SZ;               // [b][n][c] bf16
    ushort* vb  = kT + SZ;               // [b][c][n] bf16
    float*  aoT = (float*)(vb + SZ);     // [b][m][c] fp32
    float*  stats = aoT + SZ;            // mean[128], rstd[128]

    gn_stats_k<<<128, 256, 0, stream>>>(x, stats);
    qkv_k<<<dim3(64, 8, 12), 256, 0, stream>>>(x, gamma, beta, Wq, bq, Wk, bk,
                                               Wv, bv, stats, qT, kT, vb);
    attn_k<<<dim3(64, 4), 512, 0, stream>>>(qT, kT, vb, aoT);
    proj_k<<<dim3(64, 8, 4), 256, 0, stream>>>(aoT, Wp, bp, x, out);
}

// Round 6
// 1476.034 us; speedup vs baseline: 4.0642x; 1.0934x over previous
//
#include <hip/hip_runtime.h>
#include <math.h>

// AttnBlock: GroupNorm -> QKV 1x1 conv -> spatial self-attention -> proj 1x1 conv + residual
// x (4, 512, 64, 64) fp32. B=4, C=512, N=HW=4096, 32 groups of 16 ch.
// Round 6: attn restructured for occupancy — 1024 independent 4-wave blocks,
// Q pre-fragmented in LDS (VGPR<=128 -> 4 blocks/CU), XCD batch-clustering swizzle.

#define BATCH 4
#define CH    512
#define NPOS  4096
#define NGRP  32
#define GSIZE (16 * NPOS)

typedef __attribute__((ext_vector_type(8))) short bf16x8;
typedef __attribute__((ext_vector_type(4))) float f32x4;

__device__ __forceinline__ ushort f2b(float x) {   // fp32 -> bf16 RNE
    uint u = __float_as_uint(x);
    u += 0x7fff + ((u >> 16) & 1);
    return (ushort)(u >> 16);
}

// ---------------------------------------------------------------------------
// K1: GroupNorm statistics. One block per (b, g) contiguous 65536-float segment.
// ---------------------------------------------------------------------------
__global__ __launch_bounds__(256) void gn_stats_k(const float* __restrict__ x,
                                                  float* __restrict__ stats) {
    int bg = blockIdx.x;
    const float4* xp = reinterpret_cast<const float4*>(x + (size_t)bg * GSIZE);
    float s1 = 0.f, s2 = 0.f;
    for (int i = threadIdx.x; i < GSIZE / 4; i += 256) {
        float4 v = xp[i];
        s1 += v.x + v.y + v.z + v.w;
        s2 += v.x * v.x + v.y * v.y + v.z * v.z + v.w * v.w;
    }
    for (int off = 32; off > 0; off >>= 1) {
        s1 += __shfl_down(s1, off);
        s2 += __shfl_down(s2, off);
    }
    __shared__ float r1[4], r2[4];
    int wid = threadIdx.x >> 6;
    if ((threadIdx.x & 63) == 0) { r1[wid] = s1; r2[wid] = s2; }
    __syncthreads();
    if (threadIdx.x == 0) {
        float t1 = r1[0] + r1[1] + r1[2] + r1[3];
        float t2 = r2[0] + r2[1] + r2[2] + r2[3];
        float mean = t1 / (float)GSIZE;
        float var  = t2 / (float)GSIZE - mean * mean;
        stats[bg]       = mean;
        stats[128 + bg] = rsqrtf(var + 1e-6f);
    }
}

// ---------------------------------------------------------------------------
// K2: QKV GEMM, GroupNorm fused into B-tile load. bf16 outputs in MFMA layouts:
//   qT[b][m][c] (pre-scaled by 512^-0.5), kT[b][n][c], vB[b][c][n].
// grid (N/64, C/64, 3*B); block 256.
// ---------------------------------------------------------------------------
__global__ __launch_bounds__(256) void qkv_k(
    const float* __restrict__ x,
    const float* __restrict__ gamma, const float* __restrict__ beta,
    const float* __restrict__ Wq, const float* __restrict__ bq,
    const float* __restrict__ Wk, const float* __restrict__ bk,
    const float* __restrict__ Wv, const float* __restrict__ bv,
    const float* __restrict__ stats,
    ushort* __restrict__ qT, ushort* __restrict__ kT, ushort* __restrict__ vB) {
    int m0  = blockIdx.x * 64;
    int o0  = blockIdx.y * 64;
    int b   = blockIdx.z & 3;
    int sel = blockIdx.z >> 2;
    const float* W    = sel == 0 ? Wq : (sel == 1 ? Wk : Wv);
    const float* bias = sel == 0 ? bq : (sel == 1 ? bk : bv);

    __shared__ float Ws[16][68];  // [cc][o_local]
    __shared__ float Hs[16][68];  // [cc][m_local]
    int t = threadIdx.x, tx = t & 15, ty = t >> 4;
    float acc[4][4] = {};
    const float* xb = x + (size_t)b * CH * NPOS;

    // orientation: for q/k the microtile is (m x o) so the bf16 store to
    // [m][c] layout is coalesced; for v it is (o x m) for the [c][n] layout.
    const float (*At)[68] = (sel == 2) ? Ws : Hs;
    const float (*Bt)[68] = (sel == 2) ? Hs : Ws;

    for (int kc = 0; kc < CH; kc += 16) {
#pragma unroll
        for (int it = 0; it < 4; ++it) {
            int r = ty + it * 16;
            Ws[tx][r] = W[(size_t)(o0 + r) * CH + kc + tx];
        }
#pragma unroll
        for (int it = 0; it < 4; ++it) {
            int f = it * 256 + t;
            int cc = f >> 6, mm = f & 63;
            int ch = kc + cc;
            float val = xb[(size_t)ch * NPOS + m0 + mm];
            int bg = b * NGRP + (ch >> 4);
            Hs[cc][mm] = (val - stats[bg]) * stats[128 + bg] * gamma[ch] + beta[ch];
        }
        __syncthreads();
#pragma unroll 8
        for (int cc = 0; cc < 16; ++cc) {
            float4 a  = *reinterpret_cast<const float4*>(&At[cc][ty * 4]);
            float4 bb = *reinterpret_cast<const float4*>(&Bt[cc][tx * 4]);
            float av[4]  = {a.x, a.y, a.z, a.w};
            float bv4[4] = {bb.x, bb.y, bb.z, bb.w};
#pragma unroll
            for (int i = 0; i < 4; ++i)
#pragma unroll
                for (int j = 0; j < 4; ++j) acc[i][j] += av[i] * bv4[j];
        }
        __syncthreads();
    }
    if (sel == 2) {
        // rows = o (ty), cols = m (tx): vB[(b*CH+o)*NPOS + m]
#pragma unroll
        for (int i = 0; i < 4; ++i) {
            int o = o0 + ty * 4 + i;
            float bia = bias[o];
            ushort4 st = make_ushort4(f2b(acc[i][0] + bia), f2b(acc[i][1] + bia),
                                      f2b(acc[i][2] + bia), f2b(acc[i][3] + bia));
            *reinterpret_cast<ushort4*>(&vB[((size_t)b * CH + o) * NPOS + m0 + tx * 4]) = st;
        }
    } else {
        // rows = m (ty), cols = o (tx): qT/kT[(b*NPOS+m)*CH + o]
        float4 b4 = *reinterpret_cast<const float4*>(&bias[o0 + tx * 4]);
        float sc = (sel == 0) ? 0.044194173824159216f : 1.0f;  // 512^-0.5 folded into q
        ushort* outp = (sel == 0) ? qT : kT;
#pragma unroll
        for (int i = 0; i < 4; ++i) {
            int m = m0 + ty * 4 + i;
            ushort4 st = make_ushort4(f2b((acc[i][0] + b4.x) * sc),
                                      f2b((acc[i][1] + b4.y) * sc),
                                      f2b((acc[i][2] + b4.z) * sc),
                                      f2b((acc[i][3] + b4.w) * sc));
            *reinterpret_cast<ushort4*>(&outp[((size_t)b * NPOS + m) * CH + o0 + tx * 4]) = st;
        }
    }
}

// ---------------------------------------------------------------------------
// K3: flash attention on MFMA. 1024 blocks x 256 threads (4 waves).
// Block: 16 query rows (M_BLK=16). Wave nh in [0,4): scores for 16 keys
// [n0+16nh, +16), PV for c-quarter [128nh, +128). Q pre-fragmented in LDS
// (slot (ks,lane) = 16B -> conflict-free ds_read_b128, frees 64 VGPR).
// K/V fragments direct from global (L2-resident via XCD batch swizzle:
// id%8 -> XCD serves one batch only). P crosses waves via XOR-swizzled LDS.
// MFMA 16x16x32: A row=l&15,k=8*(l>>4)+j; B col=l&15; D col=l&15,row=4*(l>>4)+r.
// ---------------------------------------------------------------------------
__global__ __launch_bounds__(256, 4) void attn_k(
    const ushort* __restrict__ qT, const ushort* __restrict__ kT,
    const ushort* __restrict__ vB, float* __restrict__ aoT) {
    __shared__ ushort Qf[16 * 64 * 8];     // pre-fragmented Q: slot (ks,l), 16 KB
    __shared__ ushort P_lds[16 * 64];      // P [16 rows][64 keys] bf16, swizzled
    __shared__ float mpart[4][16], lpart[4][16];

    // bijective swizzle: XCD (id%8) serves a single batch (K+V = 8 MB working set)
    int id = blockIdx.x;
    int b  = (id & 7) >> 1;
    int m0 = (((id >> 3) << 1) | (id & 1)) << 4;

    int t = threadIdx.x, l = t & 63, nh = t >> 6;
    int lr = l & 15, lg = l >> 4;

    // stage Q pre-fragmented: slot (ks,sl) <- qT[m0+(sl&15)][ks*32+(sl>>4)*8 ..+8]
#pragma unroll
    for (int i = 0; i < 4; ++i) {
        int s = i * 256 + t;
        int sl = s & 63, ks = s >> 6;
        bf16x8 v = *(const bf16x8*)(qT + ((size_t)(b * NPOS + m0 + (sl & 15))) * CH
                                       + ks * 32 + (sl >> 4) * 8);
        *(bf16x8*)(Qf + s * 8) = v;
    }

    const ushort* kbase = kT + ((size_t)(b * NPOS + nh * 16 + lr)) * CH + lg * 8;
    const ushort* vbase = vB + ((size_t)(b * CH + nh * 128 + lr)) * NPOS + lg * 8;

    f32x4 acc[8];
#pragma unroll
    for (int i = 0; i < 8; ++i) acc[i] = (f32x4){0.f, 0.f, 0.f, 0.f};
    float m_run[4], l_run[4];
#pragma unroll
    for (int r = 0; r < 4; ++r) { m_run[r] = -1e30f; l_run[r] = 0.f; }
    __syncthreads();

    for (int it = 0; it < 64; ++it) {
        int n0 = it * 64;
        // ---- scores: S[16 rows][16 keys of this nh] ----
        f32x4 s = {0.f, 0.f, 0.f, 0.f};
        const ushort* k0 = kbase + (size_t)n0 * CH;
#pragma unroll
        for (int ks = 0; ks < 16; ++ks) {
            bf16x8 qf = *(const bf16x8*)(Qf + (ks * 64 + l) * 8);
            bf16x8 kf = *(const bf16x8*)(k0 + ks * 32);
            s = __builtin_amdgcn_mfma_f32_16x16x32_bf16(qf, kf, s, 0, 0, 0);
        }
        // ---- partial row-max over this wave's 16 keys (reduce over lr) ----
        float pm[4];
#pragma unroll
        for (int r = 0; r < 4; ++r) pm[r] = s[r];
#pragma unroll
        for (int off = 1; off < 16; off <<= 1)
#pragma unroll
            for (int r = 0; r < 4; ++r) pm[r] = fmaxf(pm[r], __shfl_xor(pm[r], off));
        if (lr == 0) {
#pragma unroll
            for (int r = 0; r < 4; ++r) mpart[nh][4 * lg + r] = pm[r];
        }
        __syncthreads();
        float mnew[4], alpha[4], p[4], ps[4];
#pragma unroll
        for (int r = 0; r < 4; ++r) {
            int row = 4 * lg + r;
            float mt = fmaxf(fmaxf(mpart[0][row], mpart[1][row]),
                             fmaxf(mpart[2][row], mpart[3][row]));
            mnew[r]  = fmaxf(m_run[r], mt);
            alpha[r] = __expf(m_run[r] - mnew[r]);
            m_run[r] = mnew[r];
            p[r]  = __expf(s[r] - mnew[r]);
            ps[r] = p[r];
        }
#pragma unroll
        for (int off = 1; off < 16; off <<= 1)
#pragma unroll
            for (int r = 0; r < 4; ++r) ps[r] += __shfl_xor(ps[r], off);
        if (lr == 0) {
#pragma unroll
            for (int r = 0; r < 4; ++r) lpart[nh][4 * lg + r] = ps[r];
        }
        // P -> LDS (bf16), byte = row*128 + col*2, XOR (row&7)<<4
#pragma unroll
        for (int r = 0; r < 4; ++r) {
            int row = 4 * lg + r;
            int cb  = (nh * 32 + lr * 2) ^ ((row & 7) << 4);
            *(ushort*)((char*)P_lds + row * 128 + cb) = f2b(p[r]);
        }
        // rescale accumulator (overlaps other waves' P writes)
#pragma unroll
        for (int cs = 0; cs < 8; ++cs) {
            acc[cs][0] *= alpha[0]; acc[cs][1] *= alpha[1];
            acc[cs][2] *= alpha[2]; acc[cs][3] *= alpha[3];
        }
        __syncthreads();
#pragma unroll
        for (int r = 0; r < 4; ++r) {
            int row = 4 * lg + r;
            l_run[r] = l_run[r] * alpha[r] +
                       (lpart[0][row] + lpart[1][row] + lpart[2][row] + lpart[3][row]);
        }
        // ---- PV: O[16 rows][128 c-quarter] += P[16][64] . V ----
        int sr = (lr & 7) << 4;
        bf16x8 pa0 = *(const bf16x8*)((const char*)P_lds + lr * 128 + ((lg * 16) ^ sr));
        bf16x8 pa1 = *(const bf16x8*)((const char*)P_lds + lr * 128 + ((64 + lg * 16) ^ sr));
        const ushort* v0 = vbase + n0;
#pragma unroll
        for (int cs = 0; cs < 8; ++cs) {
            bf16x8 vf0 = *(const bf16x8*)(v0 + (size_t)cs * 16 * NPOS);
            bf16x8 vf1 = *(const bf16x8*)(v0 + (size_t)cs * 16 * NPOS + 32);
            acc[cs] = __builtin_amdgcn_mfma_f32_16x16x32_bf16(pa0, vf0, acc[cs], 0, 0, 0);
            acc[cs] = __builtin_amdgcn_mfma_f32_16x16x32_bf16(pa1, vf1, acc[cs], 0, 0, 0);
        }
    }
    // epilogue: normalize, store fp32 aoT[b][m][c]
    float inv[4];
#pragma unroll
    for (int r = 0; r < 4; ++r) inv[r] = 1.0f / l_run[r];
#pragma unroll
    for (int cs = 0; cs < 8; ++cs)
#pragma unroll
        for (int r = 0; r < 4; ++r)
            aoT[((size_t)(b * NPOS + m0 + 4 * lg + r)) * CH + nh * 128 + cs * 16 + lr]
                = acc[cs][r] * inv[r];
}

// ---------------------------------------------------------------------------
// K4: proj 1x1 conv + bias + residual. Input aoT[b][m][c] fp32.
// ---------------------------------------------------------------------------
__global__ __launch_bounds__(256) void proj_k(const float* __restrict__ aoT,
                                              const float* __restrict__ Wp,
                                              const float* __restrict__ bp,
                                              const float* __restrict__ x,
                                              float* __restrict__ out) {
    int m0 = blockIdx.x * 64;
    int o0 = blockIdx.y * 64;
    int b  = blockIdx.z;
    __shared__ float Ws[16][68];
    __shared__ float Hs[16][68];
    int t = threadIdx.x, tx = t & 15, ty = t >> 4;
    float acc[4][4] = {};
    const float* aB = aoT + (size_t)b * NPOS * CH;

    for (int kc = 0; kc < CH; kc += 16) {
#pragma unroll
        for (int it = 0; it < 4; ++it) {
            int r = ty + it * 16;
            Ws[tx][r] = Wp[(size_t)(o0 + r) * CH + kc + tx];
        }
#pragma unroll
        for (int it = 0; it < 4; ++it) {
            int f = it * 256 + t;
            int cc = f & 15, mm = f >> 4;
            Hs[cc][mm] = aB[(size_t)(m0 + mm) * CH + kc + cc];
        }
        __syncthreads();
#pragma unroll 8
        for (int cc = 0; cc < 16; ++cc) {
            float4 a  = *reinterpret_cast<const float4*>(&Ws[cc][ty * 4]);
            float4 bb = *reinterpret_cast<const float4*>(&Hs[cc][tx * 4]);
            float av[4]  = {a.x, a.y, a.z, a.w};
            float bv4[4] = {bb.x, bb.y, bb.z, bb.w};
#pragma unroll
            for (int i = 0; i < 4; ++i)
#pragma unroll
                for (int j = 0; j < 4; ++j) acc[i][j] += av[i] * bv4[j];
        }
        __syncthreads();
    }
#pragma unroll
    for (int i = 0; i < 4; ++i) {
        int o = o0 + ty * 4 + i;
        float bia = bp[o];
        size_t base = ((size_t)b * CH + o) * NPOS + m0 + tx * 4;
        float4 xv = *reinterpret_cast<const float4*>(&x[base]);
        float4 st;
        st.x = acc[i][0] + bia + xv.x; st.y = acc[i][1] + bia + xv.y;
        st.z = acc[i][2] + bia + xv.z; st.w = acc[i][3] + bia + xv.w;
        *reinterpret_cast<float4*>(&out[base]) = st;
    }
}

// ---------------------------------------------------------------------------
extern "C" void kernel_launch(void* const* d_in, const int* in_sizes, int n_in,
                              void* d_out, int out_size, void* d_ws, size_t ws_size,
                              hipStream_t stream) {
    const float* x     = (const float*)d_in[0];
    const float* gamma = (const float*)d_in[1];
    const float* beta  = (const float*)d_in[2];
    const float* Wq    = (const float*)d_in[3];
    const float* bq    = (const float*)d_in[4];
    const float* Wk    = (const float*)d_in[5];
    const float* bk    = (const float*)d_in[6];
    const float* Wv    = (const float*)d_in[7];
    const float* bv    = (const float*)d_in[8];
    const float* Wp    = (const float*)d_in[9];
    const float* bp    = (const float*)d_in[10];
    float* out = (float*)d_out;

    const size_t SZ = (size_t)BATCH * CH * NPOS;          // 8,388,608
    const size_t need = SZ * 2 * 3 + SZ * 4 + 1024;       // ~84 MB
    if (ws_size < need) return;

    ushort* qT  = (ushort*)d_ws;         // [b][m][c] bf16 (pre-scaled)
    ushort* kT  = qT + SZ;               // [b][n][c] bf16
    ushort* vb  = kT + SZ;               // [b][c][n] bf16
    float*  aoT = (float*)(vb + SZ);     // [b][m][c] fp32
    float*  stats = aoT + SZ;            // mean[128], rstd[128]

    gn_stats_k<<<128, 256, 0, stream>>>(x, stats);
    qkv_k<<<dim3(64, 8, 12), 256, 0, stream>>>(x, gamma, beta, Wq, bq, Wk, bk,
                                               Wv, bv, stats, qT, kT, vb);
    attn_k<<<dim3(1024), 256, 0, stream>>>(qT, kT, vb, aoT);
    proj_k<<<dim3(64, 8, 4), 256, 0, stream>>>(aoT, Wp, bp, x, out);
}

// Round 7
// 936.958 us; speedup vs baseline: 6.4025x; 1.5753x over previous
//
#include <hip/hip_runtime.h>
#include <math.h>

// AttnBlock: GroupNorm -> QKV 1x1 conv -> spatial self-attention -> proj 1x1 conv + residual
// x (4, 512, 64, 64) fp32. B=4, C=512, N=HW=4096, 32 groups of 16 ch.
// Round 7: attn K/V staged through LDS via global_load_lds (coalesced, async),
// M_BLK=32/KVBLK=32, source-side chunk swizzles for conflict-free ds_read_b128.

#define BATCH 4
#define CH    512
#define NPOS  4096
#define NGRP  32
#define GSIZE (16 * NPOS)

typedef __attribute__((ext_vector_type(8))) short bf16x8;
typedef __attribute__((ext_vector_type(4))) float f32x4;

__device__ __forceinline__ ushort f2b(float x) {   // fp32 -> bf16 RNE
    uint u = __float_as_uint(x);
    u += 0x7fff + ((u >> 16) & 1);
    return (ushort)(u >> 16);
}

// async global->LDS, 16B per lane. lds base must be wave-uniform; HW writes
// base + lane*16. Global address is per-lane.
__device__ __forceinline__ void gld16(void* lds, const void* g) {
    __builtin_amdgcn_global_load_lds(
        (const __attribute__((address_space(1))) void*)g,
        (__attribute__((address_space(3))) void*)lds, 16, 0, 0);
}

// ---------------------------------------------------------------------------
// K1: GroupNorm statistics. One block per (b, g) contiguous 65536-float segment.
// ---------------------------------------------------------------------------
__global__ __launch_bounds__(256) void gn_stats_k(const float* __restrict__ x,
                                                  float* __restrict__ stats) {
    int bg = blockIdx.x;
    const float4* xp = reinterpret_cast<const float4*>(x + (size_t)bg * GSIZE);
    float s1 = 0.f, s2 = 0.f;
    for (int i = threadIdx.x; i < GSIZE / 4; i += 256) {
        float4 v = xp[i];
        s1 += v.x + v.y + v.z + v.w;
        s2 += v.x * v.x + v.y * v.y + v.z * v.z + v.w * v.w;
    }
    for (int off = 32; off > 0; off >>= 1) {
        s1 += __shfl_down(s1, off);
        s2 += __shfl_down(s2, off);
    }
    __shared__ float r1[4], r2[4];
    int wid = threadIdx.x >> 6;
    if ((threadIdx.x & 63) == 0) { r1[wid] = s1; r2[wid] = s2; }
    __syncthreads();
    if (threadIdx.x == 0) {
        float t1 = r1[0] + r1[1] + r1[2] + r1[3];
        float t2 = r2[0] + r2[1] + r2[2] + r2[3];
        float mean = t1 / (float)GSIZE;
        float var  = t2 / (float)GSIZE - mean * mean;
        stats[bg]       = mean;
        stats[128 + bg] = rsqrtf(var + 1e-6f);
    }
}

// ---------------------------------------------------------------------------
// K2: QKV GEMM, GroupNorm fused into B-tile load. bf16 outputs in MFMA layouts:
//   qT[b][m][c] (pre-scaled by 512^-0.5), kT[b][n][c], vB[b][c][n].
// grid (N/64, C/64, 3*B); block 256.
// ---------------------------------------------------------------------------
__global__ __launch_bounds__(256) void qkv_k(
    const float* __restrict__ x,
    const float* __restrict__ gamma, const float* __restrict__ beta,
    const float* __restrict__ Wq, const float* __restrict__ bq,
    const float* __restrict__ Wk, const float* __restrict__ bk,
    const float* __restrict__ Wv, const float* __restrict__ bv,
    const float* __restrict__ stats,
    ushort* __restrict__ qT, ushort* __restrict__ kT, ushort* __restrict__ vB) {
    int m0  = blockIdx.x * 64;
    int o0  = blockIdx.y * 64;
    int b   = blockIdx.z & 3;
    int sel = blockIdx.z >> 2;
    const float* W    = sel == 0 ? Wq : (sel == 1 ? Wk : Wv);
    const float* bias = sel == 0 ? bq : (sel == 1 ? bk : bv);

    __shared__ float Ws[16][68];  // [cc][o_local]
    __shared__ float Hs[16][68];  // [cc][m_local]
    int t = threadIdx.x, tx = t & 15, ty = t >> 4;
    float acc[4][4] = {};
    const float* xb = x + (size_t)b * CH * NPOS;

    const float (*At)[68] = (sel == 2) ? Ws : Hs;
    const float (*Bt)[68] = (sel == 2) ? Hs : Ws;

    for (int kc = 0; kc < CH; kc += 16) {
#pragma unroll
        for (int it = 0; it < 4; ++it) {
            int r = ty + it * 16;
            Ws[tx][r] = W[(size_t)(o0 + r) * CH + kc + tx];
        }
#pragma unroll
        for (int it = 0; it < 4; ++it) {
            int f = it * 256 + t;
            int cc = f >> 6, mm = f & 63;
            int ch = kc + cc;
            float val = xb[(size_t)ch * NPOS + m0 + mm];
            int bg = b * NGRP + (ch >> 4);
            Hs[cc][mm] = (val - stats[bg]) * stats[128 + bg] * gamma[ch] + beta[ch];
        }
        __syncthreads();
#pragma unroll 8
        for (int cc = 0; cc < 16; ++cc) {
            float4 a  = *reinterpret_cast<const float4*>(&At[cc][ty * 4]);
            float4 bb = *reinterpret_cast<const float4*>(&Bt[cc][tx * 4]);
            float av[4]  = {a.x, a.y, a.z, a.w};
            float bv4[4] = {bb.x, bb.y, bb.z, bb.w};
#pragma unroll
            for (int i = 0; i < 4; ++i)
#pragma unroll
                for (int j = 0; j < 4; ++j) acc[i][j] += av[i] * bv4[j];
        }
        __syncthreads();
    }
    if (sel == 2) {
#pragma unroll
        for (int i = 0; i < 4; ++i) {
            int o = o0 + ty * 4 + i;
            float bia = bias[o];
            ushort4 st = make_ushort4(f2b(acc[i][0] + bia), f2b(acc[i][1] + bia),
                                      f2b(acc[i][2] + bia), f2b(acc[i][3] + bia));
            *reinterpret_cast<ushort4*>(&vB[((size_t)b * CH + o) * NPOS + m0 + tx * 4]) = st;
        }
    } else {
        float4 b4 = *reinterpret_cast<const float4*>(&bias[o0 + tx * 4]);
        float sc = (sel == 0) ? 0.044194173824159216f : 1.0f;  // 512^-0.5 into q
        ushort* outp = (sel == 0) ? qT : kT;
#pragma unroll
        for (int i = 0; i < 4; ++i) {
            int m = m0 + ty * 4 + i;
            ushort4 st = make_ushort4(f2b((acc[i][0] + b4.x) * sc),
                                      f2b((acc[i][1] + b4.y) * sc),
                                      f2b((acc[i][2] + b4.z) * sc),
                                      f2b((acc[i][3] + b4.w) * sc));
            *reinterpret_cast<ushort4*>(&outp[((size_t)b * NPOS + m) * CH + o0 + tx * 4]) = st;
        }
    }
}

// ---------------------------------------------------------------------------
// K3: flash attention, LDS-staged. 512 blocks x 256 threads (4 waves).
// Block: 32 query rows, 128 KV-tiles of 32 keys. Wave w: mi=w&1 (16 rows),
// ci=w>>1 (score n-half / PV c-half).
// LDS: Ks[32][512] (1KB rows, src-chunk ^= n&7), Vs[512][32] (64B rows,
// src-chunk ^= (c>>1)&3), P[32 rows][80B stride]. All reads <=2-way banked.
// Staging: K(t+1) issued after softmax barrier (overlaps softmax+PV),
// V(t+1) after PV barrier; both drain at the iter-end __syncthreads.
// MFMA 16x16x32: A row=l&15,k=8*(l>>4)+j; B col=l&15; D col=l&15,row=4*(l>>4)+r.
// ---------------------------------------------------------------------------
__global__ __launch_bounds__(256, 2) void attn_k(
    const ushort* __restrict__ qT, const ushort* __restrict__ kT,
    const ushort* __restrict__ vB, float* __restrict__ aoT) {
    __shared__ ushort Ks[32 * 512];      // 32 KB
    __shared__ ushort Vs[512 * 32];      // 32 KB
    __shared__ ushort P_lds[32 * 40];    // 2.5 KB, 80B rows
    __shared__ float mpart[2][2][16], lpart[2][2][16];

    // XCD batch clustering: id%8 -> XCD; pairs of XCDs share one batch.
    int id = blockIdx.x;
    int b  = (id & 7) >> 1;
    int mt = ((id >> 3) << 1) | (id & 1);   // 0..127
    int m0 = mt * 32;

    int t = threadIdx.x, l = t & 63, w = t >> 6;
    int mi = w & 1, ci = w >> 1;
    int lr = l & 15, lg = l >> 4;

    const ushort* kTb = kT + (size_t)b * NPOS * CH;
    const ushort* vBb = vB + (size_t)b * CH * NPOS;

    // ---- staging helpers (per wave: 8 insts each) ----
    auto stageK = [&](int n0) {
#pragma unroll
        for (int i = 0; i < 8; ++i) {
            int n = w * 8 + i;                       // n&7 == i
            const ushort* g = kTb + (size_t)(n0 + n) * CH + (l ^ i) * 8;
            gld16(&Ks[n * 512], g);
        }
    };
    auto stageV = [&](int n0) {
#pragma unroll
        for (int i = 0; i < 8; ++i) {
            int cb = w * 128 + i * 16;
            int c  = cb + (l >> 2);
            int sc = (l & 3) ^ ((c >> 1) & 3);
            const ushort* g = vBb + (size_t)c * NPOS + n0 + sc * 8;
            gld16(&Vs[cb * 32], g);
        }
    };

    stageK(0);
    stageV(0);

    // Q fragments in registers: wave's 16 rows (mi half), full C=512.
    const ushort* qrow = qT + ((size_t)(b * NPOS + m0 + mi * 16 + lr)) * CH + lg * 8;
    bf16x8 qf[16];
#pragma unroll
    for (int ks = 0; ks < 16; ++ks) qf[ks] = *(const bf16x8*)(qrow + ks * 32);

    f32x4 acc[16];
#pragma unroll
    for (int i = 0; i < 16; ++i) acc[i] = (f32x4){0.f, 0.f, 0.f, 0.f};
    float m_run[4], l_run[4];
#pragma unroll
    for (int r = 0; r < 4; ++r) { m_run[r] = -1e30f; l_run[r] = 0.f; }
    __syncthreads();   // staged tile 0 landed

    int zk = lr & 7;   // Ks read swizzle key for this lane's key-row
    for (int nt = 0; nt < 128; ++nt) {
        // ---- scores: S[16 rows (mi)][16 keys (ci)] ----
        f32x4 s = {0.f, 0.f, 0.f, 0.f};
        const ushort* krow = &Ks[(ci * 16 + lr) * 512];
#pragma unroll
        for (int ks = 0; ks < 16; ++ks) {
            bf16x8 kf = *(const bf16x8*)(krow + ((ks * 4 + lg) ^ zk) * 8);
            s = __builtin_amdgcn_mfma_f32_16x16x32_bf16(qf[ks], kf, s, 0, 0, 0);
        }
        // row-max over this wave's 16 keys (reduce over lr)
        float pm[4];
#pragma unroll
        for (int r = 0; r < 4; ++r) pm[r] = s[r];
#pragma unroll
        for (int off = 1; off < 16; off <<= 1)
#pragma unroll
            for (int r = 0; r < 4; ++r) pm[r] = fmaxf(pm[r], __shfl_xor(pm[r], off));
        if (lr == 0) {
#pragma unroll
            for (int r = 0; r < 4; ++r) mpart[ci][mi][4 * lg + r] = pm[r];
        }
        __syncthreads();                       // b1: mpart ready, Ks reads done
        if (nt + 1 < 128) stageK((nt + 1) * 32);  // overlaps softmax+PV

        float mnew[4], alpha[4], p[4], ps[4];
#pragma unroll
        for (int r = 0; r < 4; ++r) {
            int row = 4 * lg + r;
            float mt2 = fmaxf(mpart[0][mi][row], mpart[1][mi][row]);
            mnew[r]  = fmaxf(m_run[r], mt2);
            alpha[r] = __expf(m_run[r] - mnew[r]);
            m_run[r] = mnew[r];
            p[r]  = __expf(s[r] - mnew[r]);
            ps[r] = p[r];
        }
#pragma unroll
        for (int off = 1; off < 16; off <<= 1)
#pragma unroll
            for (int r = 0; r < 4; ++r) ps[r] += __shfl_xor(ps[r], off);
        if (lr == 0) {
#pragma unroll
            for (int r = 0; r < 4; ++r) lpart[ci][mi][4 * lg + r] = ps[r];
        }
        // P -> LDS: row m_local = mi*16+4lg+r, col n = ci*16+lr, 80B row stride
#pragma unroll
        for (int r = 0; r < 4; ++r)
            P_lds[(mi * 16 + 4 * lg + r) * 40 + ci * 16 + lr] = f2b(p[r]);
        // rescale accumulator
#pragma unroll
        for (int cs = 0; cs < 16; ++cs) {
            acc[cs][0] *= alpha[0]; acc[cs][1] *= alpha[1];
            acc[cs][2] *= alpha[2]; acc[cs][3] *= alpha[3];
        }
        __syncthreads();                       // b2: P + lpart ready
#pragma unroll
        for (int r = 0; r < 4; ++r) {
            int row = 4 * lg + r;
            l_run[r] = l_run[r] * alpha[r] + (lpart[0][mi][row] + lpart[1][mi][row]);
        }
        // ---- PV: O[16 rows][256 c-half] += P[16][32] . V ----
        bf16x8 pa = *(const bf16x8*)&P_lds[(mi * 16 + lr) * 40 + lg * 8];
#pragma unroll
        for (int cs = 0; cs < 16; ++cs) {
            int c = ci * 256 + cs * 16 + lr;
            bf16x8 vf = *(const bf16x8*)&Vs[c * 32 + ((lg ^ ((c >> 1) & 3)) * 8)];
            acc[cs] = __builtin_amdgcn_mfma_f32_16x16x32_bf16(pa, vf, acc[cs], 0, 0, 0);
        }
        __syncthreads();                       // b3: Vs reads done
        if (nt + 1 < 128) stageV((nt + 1) * 32);
        __syncthreads();                       // b4: K(t+1), V(t+1) landed
    }
    // epilogue: normalize, store fp32 aoT[b][m][c]
    float inv[4];
#pragma unroll
    for (int r = 0; r < 4; ++r) inv[r] = 1.0f / l_run[r];
#pragma unroll
    for (int cs = 0; cs < 16; ++cs)
#pragma unroll
        for (int r = 0; r < 4; ++r)
            aoT[((size_t)(b * NPOS + m0 + mi * 16 + 4 * lg + r)) * CH
                + ci * 256 + cs * 16 + lr] = acc[cs][r] * inv[r];
}

// ---------------------------------------------------------------------------
// K4: proj 1x1 conv + bias + residual. Input aoT[b][m][c] fp32.
// ---------------------------------------------------------------------------
__global__ __launch_bounds__(256) void proj_k(const float* __restrict__ aoT,
                                              const float* __restrict__ Wp,
                                              const float* __restrict__ bp,
                                              const float* __restrict__ x,
                                              float* __restrict__ out) {
    int m0 = blockIdx.x * 64;
    int o0 = blockIdx.y * 64;
    int b  = blockIdx.z;
    __shared__ float Ws[16][68];
    __shared__ float Hs[16][68];
    int t = threadIdx.x, tx = t & 15, ty = t >> 4;
    float acc[4][4] = {};
    const float* aB = aoT + (size_t)b * NPOS * CH;

    for (int kc = 0; kc < CH; kc += 16) {
#pragma unroll
        for (int it = 0; it < 4; ++it) {
            int r = ty + it * 16;
            Ws[tx][r] = Wp[(size_t)(o0 + r) * CH + kc + tx];
        }
#pragma unroll
        for (int it = 0; it < 4; ++it) {
            int f = it * 256 + t;
            int cc = f & 15, mm = f >> 4;
            Hs[cc][mm] = aB[(size_t)(m0 + mm) * CH + kc + cc];
        }
        __syncthreads();
#pragma unroll 8
        for (int cc = 0; cc < 16; ++cc) {
            float4 a  = *reinterpret_cast<const float4*>(&Ws[cc][ty * 4]);
            float4 bb = *reinterpret_cast<const float4*>(&Hs[cc][tx * 4]);
            float av[4]  = {a.x, a.y, a.z, a.w};
            float bv4[4] = {bb.x, bb.y, bb.z, bb.w};
#pragma unroll
            for (int i = 0; i < 4; ++i)
#pragma unroll
                for (int j = 0; j < 4; ++j) acc[i][j] += av[i] * bv4[j];
        }
        __syncthreads();
    }
#pragma unroll
    for (int i = 0; i < 4; ++i) {
        int o = o0 + ty * 4 + i;
        float bia = bp[o];
        size_t base = ((size_t)b * CH + o) * NPOS + m0 + tx * 4;
        float4 xv = *reinterpret_cast<const float4*>(&x[base]);
        float4 st;
        st.x = acc[i][0] + bia + xv.x; st.y = acc[i][1] + bia + xv.y;
        st.z = acc[i][2] + bia + xv.z; st.w = acc[i][3] + bia + xv.w;
        *reinterpret_cast<float4*>(&out[base]) = st;
    }
}

// ---------------------------------------------------------------------------
extern "C" void kernel_launch(void* const* d_in, const int* in_sizes, int n_in,
                              void* d_out, int out_size, void* d_ws, size_t ws_size,
                              hipStream_t stream) {
    const float* x     = (const float*)d_in[0];
    const float* gamma = (const float*)d_in[1];
    const float* beta  = (const float*)d_in[2];
    const float* Wq    = (const float*)d_in[3];
    const float* bq    = (const float*)d_in[4];
    const float* Wk    = (const float*)d_in[5];
    const float* bk    = (const float*)d_in[6];
    const float* Wv    = (const float*)d_in[7];
    const float* bv    = (const float*)d_in[8];
    const float* Wp    = (const float*)d_in[9];
    const float* bp    = (const float*)d_in[10];
    float* out = (float*)d_out;

    const size_t SZ = (size_t)BATCH * CH * NPOS;          // 8,388,608
    const size_t need = SZ * 2 * 3 + SZ * 4 + 1024;       // ~84 MB
    if (ws_size < need) return;

    ushort* qT  = (ushort*)d_ws;         // [b][m][c] bf16 (pre-scaled)
    ushort* kT  = qT + SZ;               // [b][n][c] bf16
    ushort* vb  = kT + SZ;               // [b][c][n] bf16
    float*  aoT = (float*)(vb + SZ);     // [b][m][c] fp32
    float*  stats = aoT + SZ;            // mean[128], rstd[128]

    gn_stats_k<<<128, 256, 0, stream>>>(x, stats);
    qkv_k<<<dim3(64, 8, 12), 256, 0, stream>>>(x, gamma, beta, Wq, bq, Wk, bk,
                                               Wv, bv, stats, qT, kT, vb);
    attn_k<<<dim3(512), 256, 0, stream>>>(qT, kT, vb, aoT);
    proj_k<<<dim3(64, 8, 4), 256, 0, stream>>>(aoT, Wp, bp, x, out);
}

// Round 8
// 585.482 us; speedup vs baseline: 10.2460x; 1.6003x over previous
//
#include <hip/hip_runtime.h>
#include <math.h>

// AttnBlock: GroupNorm -> QKV 1x1 conv -> spatial self-attention -> proj 1x1 conv + residual
// x (4, 512, 64, 64) fp32. B=4, C=512, N=HW=4096, 32 groups of 16 ch.
// Round 8: qkv + proj on MFMA. hnT/W pre-converted to bf16; operand-swap trick
// gives v's [c][n] layout from the same registers. attn_k unchanged (r7-verified)
// except bf16 aoT epilogue.

#define BATCH 4
#define CH    512
#define NPOS  4096
#define NGRP  32
#define GSIZE (16 * NPOS)
#define WSZ   262144   // 512*512

typedef __attribute__((ext_vector_type(8))) short bf16x8;
typedef __attribute__((ext_vector_type(4))) float f32x4;

__device__ __forceinline__ ushort f2b(float x) {   // fp32 -> bf16 RNE
    uint u = __float_as_uint(x);
    u += 0x7fff + ((u >> 16) & 1);
    return (ushort)(u >> 16);
}

// async global->LDS, 16B per lane (lds base wave-uniform, HW adds lane*16)
__device__ __forceinline__ void gld16(void* lds, const void* g) {
    __builtin_amdgcn_global_load_lds(
        (const __attribute__((address_space(1))) void*)g,
        (__attribute__((address_space(3))) void*)lds, 16, 0, 0);
}

// ---------------------------------------------------------------------------
// K1: GroupNorm statistics. One block per (b, g) contiguous 65536-float segment.
// ---------------------------------------------------------------------------
__global__ __launch_bounds__(256) void gn_stats_k(const float* __restrict__ x,
                                                  float* __restrict__ stats) {
    int bg = blockIdx.x;
    const float4* xp = reinterpret_cast<const float4*>(x + (size_t)bg * GSIZE);
    float s1 = 0.f, s2 = 0.f;
    for (int i = threadIdx.x; i < GSIZE / 4; i += 256) {
        float4 v = xp[i];
        s1 += v.x + v.y + v.z + v.w;
        s2 += v.x * v.x + v.y * v.y + v.z * v.z + v.w * v.w;
    }
    for (int off = 32; off > 0; off >>= 1) {
        s1 += __shfl_down(s1, off);
        s2 += __shfl_down(s2, off);
    }
    __shared__ float r1[4], r2[4];
    int wid = threadIdx.x >> 6;
    if ((threadIdx.x & 63) == 0) { r1[wid] = s1; r2[wid] = s2; }
    __syncthreads();
    if (threadIdx.x == 0) {
        float t1 = r1[0] + r1[1] + r1[2] + r1[3];
        float t2 = r2[0] + r2[1] + r2[2] + r2[3];
        float mean = t1 / (float)GSIZE;
        float var  = t2 / (float)GSIZE - mean * mean;
        stats[bg]       = mean;
        stats[128 + bg] = rsqrtf(var + 1e-6f);
    }
}

// ---------------------------------------------------------------------------
// K2a: weights fp32 -> bf16, W4[sel][o][c], sel = q,k,v,p.
// ---------------------------------------------------------------------------
__global__ __launch_bounds__(256) void wcvt_k(
    const float* __restrict__ Wq, const float* __restrict__ Wk,
    const float* __restrict__ Wv, const float* __restrict__ Wp,
    ushort* __restrict__ W4) {
    int id = blockIdx.x;             // 512 blocks
    int sel = id >> 7, blk = id & 127;
    const float* src = sel == 0 ? Wq : (sel == 1 ? Wk : (sel == 2 ? Wv : Wp));
    const float4* s4 = (const float4*)(src + (size_t)blk * 2048);
    ushort4* d4 = (ushort4*)(W4 + (size_t)sel * WSZ + (size_t)blk * 2048);
    for (int i = threadIdx.x; i < 512; i += 256) {
        float4 v = s4[i];
        d4[i] = make_ushort4(f2b(v.x), f2b(v.y), f2b(v.z), f2b(v.w));
    }
}

// ---------------------------------------------------------------------------
// K2b: GroupNorm apply + transpose: x[b][c][m] fp32 -> hnT[b][m][c] bf16.
// grid (64 mt, 8 ct, 4 b), 64x64 tiles via LDS.
// ---------------------------------------------------------------------------
__global__ __launch_bounds__(256) void hnT_k(
    const float* __restrict__ x, const float* __restrict__ gamma,
    const float* __restrict__ beta, const float* __restrict__ stats,
    ushort* __restrict__ hnT) {
    int bm = blockIdx.x * 64, c0 = blockIdx.y * 64, b = blockIdx.z;
    __shared__ ushort Ls[64][65];
    int t = threadIdx.x, tx = t & 15, ty = t >> 4;
    const float* xb = x + ((size_t)b * CH + c0) * NPOS + bm;
#pragma unroll
    for (int it = 0; it < 4; ++it) {
        int cc = ty + it * 16;
        int ch = c0 + cc;
        int bg = b * NGRP + (ch >> 4);
        float ga = stats[128 + bg] * gamma[ch];
        float be = beta[ch] - stats[bg] * ga;
        float4 v = *(const float4*)(xb + (size_t)cc * NPOS + tx * 4);
        Ls[cc][tx * 4 + 0] = f2b(v.x * ga + be);
        Ls[cc][tx * 4 + 1] = f2b(v.y * ga + be);
        Ls[cc][tx * 4 + 2] = f2b(v.z * ga + be);
        Ls[cc][tx * 4 + 3] = f2b(v.w * ga + be);
    }
    __syncthreads();
#pragma unroll
    for (int it = 0; it < 4; ++it) {
        int mm = ty + it * 16;
        ushort4 o;
        o.x = Ls[tx * 4 + 0][mm];
        o.y = Ls[tx * 4 + 1][mm];
        o.z = Ls[tx * 4 + 2][mm];
        o.w = Ls[tx * 4 + 3][mm];
        *(ushort4*)(hnT + ((size_t)(b * NPOS) + bm + mm) * CH + c0 + tx * 4) = o;
    }
}

// ---------------------------------------------------------------------------
// K3: QKV GEMM on MFMA, no LDS (hnT+W4 are L2-resident bf16 in fragment-
// friendly layouts). grid (64 mt, 8 ot, 4 b), 4 waves; wave tile 32m x 32o,
// all 3 outputs. Same regs serve as A (rows) for q/k and B (cols) for v.
// Outputs: qT[b][m][o] (pre-scaled), kT[b][m][o], vB[b][o][m].
// ---------------------------------------------------------------------------
__global__ __launch_bounds__(256) void qkv3_k(
    const ushort* __restrict__ hnT, const ushort* __restrict__ W4,
    const float* __restrict__ bq, const float* __restrict__ bk,
    const float* __restrict__ bv,
    ushort* __restrict__ qT, ushort* __restrict__ kT, ushort* __restrict__ vB) {
    int bm = blockIdx.x * 64, bo = blockIdx.y * 64, b = blockIdx.z;
    int t = threadIdx.x, l = t & 63, w = t >> 6;
    int wr = w & 1, wc = w >> 1;
    int lr = l & 15, lg = l >> 4;

    const ushort* ha  = hnT + ((size_t)(b * NPOS) + bm + wr * 32 + lr) * CH + lg * 8;
    const ushort* wqp = W4 + (size_t)(bo + wc * 32 + lr) * CH + lg * 8;
    const ushort* wkp = wqp + WSZ;
    const ushort* wvp = wkp + WSZ;

    f32x4 aq[2][2], ak[2][2], av[2][2];
#pragma unroll
    for (int i = 0; i < 2; ++i)
#pragma unroll
        for (int j = 0; j < 2; ++j) {
            aq[i][j] = (f32x4){0.f, 0.f, 0.f, 0.f};
            ak[i][j] = (f32x4){0.f, 0.f, 0.f, 0.f};
            av[i][j] = (f32x4){0.f, 0.f, 0.f, 0.f};
        }
#pragma unroll
    for (int c0 = 0; c0 < CH; c0 += 32) {
        bf16x8 a0 = *(const bf16x8*)(ha + c0);
        bf16x8 a1 = *(const bf16x8*)(ha + 16 * CH + c0);
        bf16x8 q0 = *(const bf16x8*)(wqp + c0);
        bf16x8 q1 = *(const bf16x8*)(wqp + 16 * CH + c0);
        bf16x8 k0 = *(const bf16x8*)(wkp + c0);
        bf16x8 k1 = *(const bf16x8*)(wkp + 16 * CH + c0);
        bf16x8 v0 = *(const bf16x8*)(wvp + c0);
        bf16x8 v1 = *(const bf16x8*)(wvp + 16 * CH + c0);
        aq[0][0] = __builtin_amdgcn_mfma_f32_16x16x32_bf16(a0, q0, aq[0][0], 0, 0, 0);
        aq[0][1] = __builtin_amdgcn_mfma_f32_16x16x32_bf16(a0, q1, aq[0][1], 0, 0, 0);
        aq[1][0] = __builtin_amdgcn_mfma_f32_16x16x32_bf16(a1, q0, aq[1][0], 0, 0, 0);
        aq[1][1] = __builtin_amdgcn_mfma_f32_16x16x32_bf16(a1, q1, aq[1][1], 0, 0, 0);
        ak[0][0] = __builtin_amdgcn_mfma_f32_16x16x32_bf16(a0, k0, ak[0][0], 0, 0, 0);
        ak[0][1] = __builtin_amdgcn_mfma_f32_16x16x32_bf16(a0, k1, ak[0][1], 0, 0, 0);
        ak[1][0] = __builtin_amdgcn_mfma_f32_16x16x32_bf16(a1, k0, ak[1][0], 0, 0, 0);
        ak[1][1] = __builtin_amdgcn_mfma_f32_16x16x32_bf16(a1, k1, ak[1][1], 0, 0, 0);
        av[0][0] = __builtin_amdgcn_mfma_f32_16x16x32_bf16(v0, a0, av[0][0], 0, 0, 0);
        av[0][1] = __builtin_amdgcn_mfma_f32_16x16x32_bf16(v0, a1, av[0][1], 0, 0, 0);
        av[1][0] = __builtin_amdgcn_mfma_f32_16x16x32_bf16(v1, a0, av[1][0], 0, 0, 0);
        av[1][1] = __builtin_amdgcn_mfma_f32_16x16x32_bf16(v1, a1, av[1][1], 0, 0, 0);
    }
    const float sc = 0.044194173824159216f;   // 512^-0.5 folded into q
#pragma unroll
    for (int j = 0; j < 2; ++j) {
        int o = bo + wc * 32 + j * 16 + lr;
        float bqv = bq[o], bkv = bk[o];
#pragma unroll
        for (int i = 0; i < 2; ++i)
#pragma unroll
            for (int r = 0; r < 4; ++r) {
                int m = bm + wr * 32 + i * 16 + 4 * lg + r;
                size_t base = ((size_t)(b * NPOS) + m) * CH + o;
                qT[base] = f2b((aq[i][j][r] + bqv) * sc);
                kT[base] = f2b(ak[i][j][r] + bkv);
            }
    }
#pragma unroll
    for (int i = 0; i < 2; ++i)
#pragma unroll
        for (int r = 0; r < 4; ++r) {
            int o = bo + wc * 32 + i * 16 + 4 * lg + r;
            float bvv = bv[o];
#pragma unroll
            for (int j = 0; j < 2; ++j) {
                int m = bm + wr * 32 + j * 16 + lr;
                vB[((size_t)(b * CH) + o) * NPOS + m] = f2b(av[i][j][r] + bvv);
            }
        }
}

// ---------------------------------------------------------------------------
// K4: flash attention, LDS-staged (round-7 verified). 512 blocks x 4 waves.
// Epilogue now writes bf16 aoT[b][m][c].
// ---------------------------------------------------------------------------
__global__ __launch_bounds__(256, 2) void attn_k(
    const ushort* __restrict__ qT, const ushort* __restrict__ kT,
    const ushort* __restrict__ vB, ushort* __restrict__ aoT) {
    __shared__ ushort Ks[32 * 512];      // 32 KB
    __shared__ ushort Vs[512 * 32];      // 32 KB
    __shared__ ushort P_lds[32 * 40];    // 80B rows
    __shared__ float mpart[2][2][16], lpart[2][2][16];

    int id = blockIdx.x;
    int b  = (id & 7) >> 1;
    int mt = ((id >> 3) << 1) | (id & 1);
    int m0 = mt * 32;

    int t = threadIdx.x, l = t & 63, w = t >> 6;
    int mi = w & 1, ci = w >> 1;
    int lr = l & 15, lg = l >> 4;

    const ushort* kTb = kT + (size_t)b * NPOS * CH;
    const ushort* vBb = vB + (size_t)b * CH * NPOS;

    auto stageK = [&](int n0) {
#pragma unroll
        for (int i = 0; i < 8; ++i) {
            int n = w * 8 + i;
            const ushort* g = kTb + (size_t)(n0 + n) * CH + (l ^ i) * 8;
            gld16(&Ks[n * 512], g);
        }
    };
    auto stageV = [&](int n0) {
#pragma unroll
        for (int i = 0; i < 8; ++i) {
            int cb = w * 128 + i * 16;
            int c  = cb + (l >> 2);
            int sc = (l & 3) ^ ((c >> 1) & 3);
            const ushort* g = vBb + (size_t)c * NPOS + n0 + sc * 8;
            gld16(&Vs[cb * 32], g);
        }
    };

    stageK(0);
    stageV(0);

    const ushort* qrow = qT + ((size_t)(b * NPOS + m0 + mi * 16 + lr)) * CH + lg * 8;
    bf16x8 qf[16];
#pragma unroll
    for (int ks = 0; ks < 16; ++ks) qf[ks] = *(const bf16x8*)(qrow + ks * 32);

    f32x4 acc[16];
#pragma unroll
    for (int i = 0; i < 16; ++i) acc[i] = (f32x4){0.f, 0.f, 0.f, 0.f};
    float m_run[4], l_run[4];
#pragma unroll
    for (int r = 0; r < 4; ++r) { m_run[r] = -1e30f; l_run[r] = 0.f; }
    __syncthreads();

    int zk = lr & 7;
    for (int nt = 0; nt < 128; ++nt) {
        f32x4 s = {0.f, 0.f, 0.f, 0.f};
        const ushort* krow = &Ks[(ci * 16 + lr) * 512];
#pragma unroll
        for (int ks = 0; ks < 16; ++ks) {
            bf16x8 kf = *(const bf16x8*)(krow + ((ks * 4 + lg) ^ zk) * 8);
            s = __builtin_amdgcn_mfma_f32_16x16x32_bf16(qf[ks], kf, s, 0, 0, 0);
        }
        float pm[4];
#pragma unroll
        for (int r = 0; r < 4; ++r) pm[r] = s[r];
#pragma unroll
        for (int off = 1; off < 16; off <<= 1)
#pragma unroll
            for (int r = 0; r < 4; ++r) pm[r] = fmaxf(pm[r], __shfl_xor(pm[r], off));
        if (lr == 0) {
#pragma unroll
            for (int r = 0; r < 4; ++r) mpart[ci][mi][4 * lg + r] = pm[r];
        }
        __syncthreads();
        if (nt + 1 < 128) stageK((nt + 1) * 32);

        float mnew[4], alpha[4], p[4], ps[4];
#pragma unroll
        for (int r = 0; r < 4; ++r) {
            int row = 4 * lg + r;
            float mt2 = fmaxf(mpart[0][mi][row], mpart[1][mi][row]);
            mnew[r]  = fmaxf(m_run[r], mt2);
            alpha[r] = __expf(m_run[r] - mnew[r]);
            m_run[r] = mnew[r];
            p[r]  = __expf(s[r] - mnew[r]);
            ps[r] = p[r];
        }
#pragma unroll
        for (int off = 1; off < 16; off <<= 1)
#pragma unroll
            for (int r = 0; r < 4; ++r) ps[r] += __shfl_xor(ps[r], off);
        if (lr == 0) {
#pragma unroll
            for (int r = 0; r < 4; ++r) lpart[ci][mi][4 * lg + r] = ps[r];
        }
#pragma unroll
        for (int r = 0; r < 4; ++r)
            P_lds[(mi * 16 + 4 * lg + r) * 40 + ci * 16 + lr] = f2b(p[r]);
#pragma unroll
        for (int cs = 0; cs < 16; ++cs) {
            acc[cs][0] *= alpha[0]; acc[cs][1] *= alpha[1];
            acc[cs][2] *= alpha[2]; acc[cs][3] *= alpha[3];
        }
        __syncthreads();
#pragma unroll
        for (int r = 0; r < 4; ++r) {
            int row = 4 * lg + r;
            l_run[r] = l_run[r] * alpha[r] + (lpart[0][mi][row] + lpart[1][mi][row]);
        }
        bf16x8 pa = *(const bf16x8*)&P_lds[(mi * 16 + lr) * 40 + lg * 8];
#pragma unroll
        for (int cs = 0; cs < 16; ++cs) {
            int c = ci * 256 + cs * 16 + lr;
            bf16x8 vf = *(const bf16x8*)&Vs[c * 32 + ((lg ^ ((c >> 1) & 3)) * 8)];
            acc[cs] = __builtin_amdgcn_mfma_f32_16x16x32_bf16(pa, vf, acc[cs], 0, 0, 0);
        }
        __syncthreads();
        if (nt + 1 < 128) stageV((nt + 1) * 32);
        __syncthreads();
    }
    float inv[4];
#pragma unroll
    for (int r = 0; r < 4; ++r) inv[r] = 1.0f / l_run[r];
#pragma unroll
    for (int cs = 0; cs < 16; ++cs)
#pragma unroll
        for (int r = 0; r < 4; ++r)
            aoT[((size_t)(b * NPOS + m0 + mi * 16 + 4 * lg + r)) * CH
                + ci * 256 + cs * 16 + lr] = f2b(acc[cs][r] * inv[r]);
}

// ---------------------------------------------------------------------------
// K5: proj on MFMA + bias + residual. A=Wp (rows o), B=aoT bf16 (cols m).
// grid (64 mt, 8 ot, 4 b), 4 waves, wave tile 32o x 32m. No LDS.
// ---------------------------------------------------------------------------
__global__ __launch_bounds__(256) void proj_k(
    const ushort* __restrict__ aoT, const ushort* __restrict__ W4,
    const float* __restrict__ bp, const float* __restrict__ x,
    float* __restrict__ out) {
    int bm = blockIdx.x * 64, bo = blockIdx.y * 64, b = blockIdx.z;
    int t = threadIdx.x, l = t & 63, w = t >> 6;
    int orh = w & 1, mc = w >> 1;
    int lr = l & 15, lg = l >> 4;

    const ushort* wp = W4 + 3 * (size_t)WSZ + (size_t)(bo + orh * 32 + lr) * CH + lg * 8;
    const ushort* ab = aoT + ((size_t)(b * NPOS) + bm + mc * 32 + lr) * CH + lg * 8;

    f32x4 ac[2][2];
#pragma unroll
    for (int i = 0; i < 2; ++i)
#pragma unroll
        for (int j = 0; j < 2; ++j) ac[i][j] = (f32x4){0.f, 0.f, 0.f, 0.f};
#pragma unroll
    for (int c0 = 0; c0 < CH; c0 += 32) {
        bf16x8 w0 = *(const bf16x8*)(wp + c0);
        bf16x8 w1 = *(const bf16x8*)(wp + 16 * CH + c0);
        bf16x8 b0 = *(const bf16x8*)(ab + c0);
        bf16x8 b1 = *(const bf16x8*)(ab + 16 * CH + c0);
        ac[0][0] = __builtin_amdgcn_mfma_f32_16x16x32_bf16(w0, b0, ac[0][0], 0, 0, 0);
        ac[0][1] = __builtin_amdgcn_mfma_f32_16x16x32_bf16(w0, b1, ac[0][1], 0, 0, 0);
        ac[1][0] = __builtin_amdgcn_mfma_f32_16x16x32_bf16(w1, b0, ac[1][0], 0, 0, 0);
        ac[1][1] = __builtin_amdgcn_mfma_f32_16x16x32_bf16(w1, b1, ac[1][1], 0, 0, 0);
    }
#pragma unroll
    for (int i = 0; i < 2; ++i)
#pragma unroll
        for (int r = 0; r < 4; ++r) {
            int o = bo + orh * 32 + i * 16 + 4 * lg + r;
            float bpv = bp[o];
#pragma unroll
            for (int j = 0; j < 2; ++j) {
                int m = bm + mc * 32 + j * 16 + lr;
                size_t base = ((size_t)(b * CH) + o) * NPOS + m;
                out[base] = ac[i][j][r] + bpv + x[base];
            }
        }
}

// ---------------------------------------------------------------------------
extern "C" void kernel_launch(void* const* d_in, const int* in_sizes, int n_in,
                              void* d_out, int out_size, void* d_ws, size_t ws_size,
                              hipStream_t stream) {
    const float* x     = (const float*)d_in[0];
    const float* gamma = (const float*)d_in[1];
    const float* beta  = (const float*)d_in[2];
    const float* Wq    = (const float*)d_in[3];
    const float* bq    = (const float*)d_in[4];
    const float* Wk    = (const float*)d_in[5];
    const float* bk    = (const float*)d_in[6];
    const float* Wv    = (const float*)d_in[7];
    const float* bv    = (const float*)d_in[8];
    const float* Wp    = (const float*)d_in[9];
    const float* bp    = (const float*)d_in[10];
    float* out = (float*)d_out;

    const size_t SZ = (size_t)BATCH * CH * NPOS;               // 8,388,608
    const size_t need = (5 * SZ + 4 * WSZ) * 2 + 1024;         // ~86 MB
    if (ws_size < need) return;

    ushort* qT  = (ushort*)d_ws;          // [b][m][o] bf16 (pre-scaled)
    ushort* kT  = qT + SZ;                // [b][m][o] bf16
    ushort* vb  = kT + SZ;                // [b][o][m] bf16
    ushort* hnT = vb + SZ;                // [b][m][c] bf16
    ushort* aoT = hnT + SZ;               // [b][m][c] bf16
    ushort* W4  = aoT + SZ;               // [4][512][512] bf16
    float*  stats = (float*)(W4 + 4 * (size_t)WSZ);

    gn_stats_k<<<128, 256, 0, stream>>>(x, stats);
    wcvt_k<<<512, 256, 0, stream>>>(Wq, Wk, Wv, Wp, W4);
    hnT_k<<<dim3(64, 8, 4), 256, 0, stream>>>(x, gamma, beta, stats, hnT);
    qkv3_k<<<dim3(64, 8, 4), 256, 0, stream>>>(hnT, W4, bq, bk, bv, qT, kT, vb);
    attn_k<<<dim3(512), 256, 0, stream>>>(qT, kT, vb, aoT);
    proj_k<<<dim3(64, 8, 4), 256, 0, stream>>>(aoT, W4, bp, x, out);
}